// Round 6
// baseline (137.064 us; speedup 1.0000x reference)
//
#include <hip/hip_runtime.h>

// SLAYER 2-layer SNN, MI355X. Round-6: split conv (9216 waves, latency-immune)
// from scan (2304 waves, register-resident). psp commutes with conv2d ->
// convs see BINARY spike trains (bit-packed).
//   KA: floats -> bitT[y][xw][t] (uint32, bit = x%32)          [1152 blocks]
//   K1: conv1(5x5, row-LUT, lanes=t) -> ct1 f32 [strip][col][t] [2304 blocks]
//   K2: scan1 (lane=px, c[64] in regs) -> s1h halfwords          [576 blocks]
//   K3: conv2 pattern-only -> ct2p ushort [strip][col][t]       [2304 blocks]
//   K4: lut3[512] gather + scan2 -> float out (256B/lane)        [576 blocks]
// Scan & LUT arithmetic bitwise-identical to rounds 0-5 (absmax == 0 each).

#define HH   192
#define WW   192
#define NIMG 4
#define TT   64
#define NT   256
#define XW   6     // uint32 x-words per image row
#define XH   12    // 16-bit x-halfwords per image row
#define SPR  12    // 16-px strips per image row

#define E_D 2.718281828459045
static constexpr float D1  = (float)0.36787944117144233;   // exp(-1/1)
static constexpr float CP1 = (float)(E_D);
static constexpr float DR1 = (float)0.36787944117144233;
static constexpr float CR1 = (float)(-30.0 * E_D);
static constexpr float D2  = (float)0.6065306597126334;    // exp(-1/2)
static constexpr float CP2 = (float)(E_D * 0.5);
static constexpr float DR2 = (float)0.6065306597126334;
static constexpr float CR2 = (float)(-50.0 * E_D * 0.5);
static constexpr float TH1 = 30.0f;
static constexpr float TH2 = 50.0f;

// ---------------- KA: float spikes -> x-transposed bit words ---------------
__global__ __launch_bounds__(NT)
void ka_pack(const float* __restrict__ in, unsigned* __restrict__ bitT) {
    const int gw = blockIdx.x * (NT / 64) + (threadIdx.x >> 6);
    const int ln = threadIdx.x & 63;
    const int xw = gw % XW;
    const int ny = gw / XW;                 // n*HH + y
    const float* src = in + ((size_t)ny * WW + xw * 32) * TT + ln;
    unsigned w = 0u;
#pragma unroll
    for (int x = 0; x < 32; x++) {
        const float v = src[(size_t)x * TT];
        w |= (v != 0.f) ? (1u << x) : 0u;
    }
    bitT[((size_t)ny * XW + xw) * TT + ln] = w;
}

// ---------------- K1: conv1 -> ct1 f32, one wave per 16-px strip -----------
__global__ __launch_bounds__(NT)
void k1_conv1(const unsigned* __restrict__ bitT, const float* __restrict__ w1g,
              float* __restrict__ ct1) {
    __shared__ float lut[5 * 32];
    const int n = blockIdx.z, gy = blockIdx.y * 4 + (threadIdx.x >> 6);
    const int xs = blockIdx.x, ln = threadIdx.x & 63;
    const int tid = threadIdx.x;

    if (tid < 160) {                        // lut[r*32+p] = sum_j w1[r][j]*bit_j(p)
        const int r = tid >> 5, p = tid & 31;
        float s = 0.f;
#pragma unroll
        for (int j = 0; j < 5; j++)
            if ((p >> j) & 1) s += w1g[r * 5 + j];
        lut[tid] = s;
    }

    // Window bits c=0..19 <-> gx = xs*16-2+c, lane = t. Shift s in {30,14}.
    const int x0 = xs * 16;
    const int a = (x0 - 2) >> 5;
    const int s = (x0 - 2) & 31;
    unsigned w20[5];
#pragma unroll
    for (int dy = 0; dy < 5; dy++) {
        const int yy = gy - 2 + dy;
        unsigned wa = 0u, wb = 0u;
        if (yy >= 0 && yy < HH) {
            const unsigned* rp = bitT + ((size_t)(n * HH + yy) * XW) * TT + ln;
            if (a >= 0)     wa = rp[(size_t)a * TT];
            if (a + 1 < XW) wb = rp[(size_t)(a + 1) * TT];
        }
        w20[dy] = (wa >> s) | (wb << (32 - s));
    }
    __syncthreads();

    float* op = ct1 + ((size_t)(n * HH + gy) * SPR + xs) * 16 * TT + ln;
#pragma unroll
    for (int col = 0; col < 16; col++) {
        const float c =
            ((lut[  0 + ((w20[0] >> col) & 31)]
            + lut[ 32 + ((w20[1] >> col) & 31)])
            + (lut[ 64 + ((w20[2] >> col) & 31)]
            +  lut[ 96 + ((w20[3] >> col) & 31)]))
            +  lut[128 + ((w20[4] >> col) & 31)];
        op[(size_t)col * TT] = c;           // 256B coalesced store
    }
}

// ---------------- K2: scan1 (lane = px) -> s1h halfwords -------------------
__global__ __launch_bounds__(NT, 1)
void k2_scan1(const float* __restrict__ ct1, unsigned short* __restrict__ s1h) {
    __shared__ uint2 tb[NT];
    const int n = blockIdx.z, by = blockIdx.y, bx = blockIdx.x;
    const int tid = threadIdx.x;
    const int y = by * 16 + (tid >> 4);

    // per-lane 256B contiguous: 16 x dwordx4 loads into c[64]
    const float4* p = reinterpret_cast<const float4*>(
        ct1 + (((size_t)(n * HH + y) * SPR + bx) * 16 + (tid & 15)) * TT);
    float c[TT];
#pragma unroll
    for (int j = 0; j < 16; j++) {
        const float4 v = p[j];
        c[4 * j + 0] = v.x; c[4 * j + 1] = v.y;
        c[4 * j + 2] = v.z; c[4 * j + 3] = v.w;
    }

    float u1 = 0.f, v1 = 0.f, ur = 0.f, vr = 0.f;
    unsigned slo = 0u, shi = 0u;
#pragma unroll
    for (int tc = 0; tc < TT; tc += 8) {
#pragma unroll
        for (int j = 0; j < 8; j++) {
            v1 = D1 * (v1 + u1);
            const float pp = CP1 * v1;
            u1 = D1 * u1 + c[tc + j];
            vr = DR1 * (vr + ur);
            const float m = pp + CR1 * vr;
            const bool sp = (m >= TH1);
            ur = DR1 * ur + (sp ? 1.f : 0.f);
            const unsigned bit = sp ? (1u << ((tc + j) & 31)) : 0u;
            if (tc < 32) slo |= bit;
            else         shi |= bit;
        }
    }
    tb[tid] = make_uint2(slo, shi);
    __syncthreads();

    // transpose to halfwords, lanes = t (round-5 Phase T)
    const int wv = tid >> 6, ln = tid & 63;
#pragma unroll
    for (int rp = 0; rp < 4; rp++) {
        const int yl = wv * 4 + rp;
        unsigned h = 0u;
#pragma unroll
        for (int x = 0; x < 16; x++) {
            const uint2 b = tb[yl * 16 + x];
            const unsigned w = (ln < 32) ? b.x : b.y;
            h |= ((w >> (ln & 31)) & 1u) << x;
        }
        s1h[((size_t)(n * HH + by * 16 + yl) * XH + bx) * TT + ln] =
            (unsigned short)h;
    }
}

// ---------------- K3: conv2 patterns (9-bit) -> ct2p ushort ----------------
__global__ __launch_bounds__(NT)
void k3_conv2(const unsigned short* __restrict__ s1h,
              unsigned short* __restrict__ ct2p) {
    const int n = blockIdx.z, gy = blockIdx.y * 4 + (threadIdx.x >> 6);
    const int tx = blockIdx.x, ln = threadIdx.x & 63;

    unsigned w18[3];
#pragma unroll
    for (int dy = 0; dy < 3; dy++) {
        const int yy = gy - 1 + dy;
        unsigned hm = 0u, h0 = 0u, hp = 0u;
        if (yy >= 0 && yy < HH) {
            const unsigned short* rp =
                s1h + ((size_t)(n * HH + yy) * XH) * TT + ln;
            if (tx > 0)      hm = rp[(size_t)(tx - 1) * TT];
            h0 = rp[(size_t)tx * TT];
            if (tx + 1 < XH) hp = rp[(size_t)(tx + 1) * TT];
        }
        w18[dy] = (hm >> 15) | (h0 << 1) | ((hp & 1u) << 17);
    }

    unsigned short* op =
        ct2p + ((size_t)(n * HH + gy) * SPR + tx) * 16 * TT + ln;
#pragma unroll
    for (int col = 0; col < 16; col++) {
        const unsigned pat = ((w18[0] >> col) & 7)
                           | (((w18[1] >> col) & 7) << 3)
                           | (((w18[2] >> col) & 7) << 6);
        op[(size_t)col * TT] = (unsigned short)pat;   // 128B coalesced store
    }
}

// ---------------- K4: lut3 gather + scan2 -> float spikes ------------------
__global__ __launch_bounds__(NT, 1)
void k4_scan2(const unsigned short* __restrict__ ct2p,
              const float* __restrict__ w2g, float* __restrict__ out) {
    __shared__ float lut3[512];
    const int n = blockIdx.z, by = blockIdx.y, bx = blockIdx.x;
    const int tid = threadIdx.x;

    // lut3[e] = (l0+l1)+l2, each lk built in j-order -> bitwise = round-5 sum
#pragma unroll
    for (int e = tid; e < 512; e += NT) {
        float l0 = 0.f, l1 = 0.f, l2 = 0.f;
#pragma unroll
        for (int j = 0; j < 3; j++) {
            if ((e >> j) & 1)       l0 += w2g[j];
            if ((e >> (3 + j)) & 1) l1 += w2g[3 + j];
            if ((e >> (6 + j)) & 1) l2 += w2g[6 + j];
        }
        lut3[e] = (l0 + l1) + l2;
    }
    __syncthreads();

    const int y = by * 16 + (tid >> 4), x = bx * 16 + (tid & 15);
    const uint4* pp = reinterpret_cast<const uint4*>(
        ct2p + (((size_t)(n * HH + y) * SPR + bx) * 16 + (tid & 15)) * TT);
    uint4 pr[8];
#pragma unroll
    for (int j = 0; j < 8; j++) pr[j] = pp[j];      // 128B/lane, pipelined

    float l[TT];
#pragma unroll
    for (int j = 0; j < 8; j++) {
        const unsigned q[4] = {pr[j].x, pr[j].y, pr[j].z, pr[j].w};
#pragma unroll
        for (int h = 0; h < 4; h++) {
            l[j * 8 + 2 * h + 0] = lut3[q[h] & 0x1ffu];
            l[j * 8 + 2 * h + 1] = lut3[(q[h] >> 16) & 0x1ffu];
        }
    }

    float u2 = 0.f, v2 = 0.f, ur2 = 0.f, vr2 = 0.f;
    unsigned olo = 0u, ohi = 0u;
#pragma unroll
    for (int tc = 0; tc < TT; tc += 8) {
#pragma unroll
        for (int j = 0; j < 8; j++) {
            v2 = D2 * (v2 + u2);
            const float p = CP2 * v2;
            u2 = D2 * u2 + l[tc + j];
            vr2 = DR2 * (vr2 + ur2);
            const float m = p + CR2 * vr2;
            const bool sp = (m >= TH2);
            ur2 = DR2 * ur2 + (sp ? 1.f : 0.f);
            const unsigned bit = sp ? (1u << ((tc + j) & 31)) : 0u;
            if (tc < 32) olo |= bit;
            else         ohi |= bit;
        }
    }

    // per-lane 256B contiguous float4 stores (round-0 Phase C)
    float* op = out + ((size_t)(n * HH + y) * WW + x) * TT;
#pragma unroll
    for (int c = 0; c < 16; c++) {
        const unsigned word = (c < 8) ? olo : ohi;
        const int sh = (4 * c) & 31;
        float4 v;
        v.x = (float)((word >> (sh + 0)) & 1u);
        v.y = (float)((word >> (sh + 1)) & 1u);
        v.z = (float)((word >> (sh + 2)) & 1u);
        v.w = (float)((word >> (sh + 3)) & 1u);
        reinterpret_cast<float4*>(op)[c] = v;
    }
}

extern "C" void kernel_launch(void* const* d_in, const int* in_sizes, int n_in,
                              void* d_out, int out_size, void* d_ws, size_t ws_size,
                              hipStream_t stream) {
    const float* in = (const float*)d_in[0];   // (4,1,192,192,64) f32 spikes
    const float* w1 = (const float*)d_in[1];   // (1,1,5,5)
    const float* w2 = (const float*)d_in[2];   // (1,1,3,3)
    float* out = (float*)d_out;                // (4,1,192,192,64) f32 spikes

    char* ws = (char*)d_ws;
    unsigned*       bitT = (unsigned*)ws;                        // 1.18 MB
    unsigned short* s1h  = (unsigned short*)(ws + (2ull << 20)); // 1.18 MB
    float*          ct1  = (float*)(ws + (4ull << 20));          // 37.7 MB
    unsigned short* ct2p = (unsigned short*)(ws + (44ull << 20));// 18.9 MB

    const int ka_blocks = (NIMG * HH * XW) / (NT / 64);          // 1152
    dim3 cgrid(SPR, HH / 4, NIMG);                               // 12 x 48 x 4
    dim3 sgrid(SPR, HH / 16, NIMG);                              // 12 x 12 x 4
    ka_pack <<<ka_blocks, NT, 0, stream>>>(in, bitT);
    k1_conv1<<<cgrid, NT, 0, stream>>>(bitT, w1, ct1);
    k2_scan1<<<sgrid, NT, 0, stream>>>(ct1, s1h);
    k3_conv2<<<cgrid, NT, 0, stream>>>(s1h, ct2p);
    k4_scan2<<<sgrid, NT, 0, stream>>>(ct2p, w2, out);
}

// Round 7
// 125.988 us; speedup vs baseline: 1.0879x; 1.0879x over previous
//
#include <hip/hip_runtime.h>

// SLAYER 2-layer SNN, MI355X. Round-7: round-6 structure, K4 store epilogue
// fixed back to LDS-transpose + lanes=t coalesced stores (round-6 lesson:
// per-lane float4 stores at 256B lane stride caused 2.8x write amplification,
// WRITE_SIZE 105 MB vs 37.7 MB ideal, K4 46 us).
//   KA: floats -> bitT[y][xw][t] (uint32, bit = x%32)          [1152 blocks]
//   K1: conv1(5x5, row-LUT, lanes=t) -> ct1 f32 [strip][col][t] [2304 blocks]
//   K2: scan1 (lane=px, c[64] in regs) -> s1h halfwords          [576 blocks]
//   K3: conv2 pattern-only -> ct2p ushort [strip][col][t]       [2304 blocks]
//   K4: lut3[512] gather + scan2 -> LDS transpose -> coalesced out [576 blocks]
// Scan & LUT arithmetic bitwise-identical to rounds 0-6 (absmax == 0 each).

#define HH   192
#define WW   192
#define NIMG 4
#define TT   64
#define NT   256
#define XW   6     // uint32 x-words per image row
#define XH   12    // 16-bit x-halfwords per image row
#define SPR  12    // 16-px strips per image row

#define E_D 2.718281828459045
static constexpr float D1  = (float)0.36787944117144233;   // exp(-1/1)
static constexpr float CP1 = (float)(E_D);
static constexpr float DR1 = (float)0.36787944117144233;
static constexpr float CR1 = (float)(-30.0 * E_D);
static constexpr float D2  = (float)0.6065306597126334;    // exp(-1/2)
static constexpr float CP2 = (float)(E_D * 0.5);
static constexpr float DR2 = (float)0.6065306597126334;
static constexpr float CR2 = (float)(-50.0 * E_D * 0.5);
static constexpr float TH1 = 30.0f;
static constexpr float TH2 = 50.0f;

// ---------------- KA: float spikes -> x-transposed bit words ---------------
__global__ __launch_bounds__(NT)
void ka_pack(const float* __restrict__ in, unsigned* __restrict__ bitT) {
    const int gw = blockIdx.x * (NT / 64) + (threadIdx.x >> 6);
    const int ln = threadIdx.x & 63;
    const int xw = gw % XW;
    const int ny = gw / XW;                 // n*HH + y
    const float* src = in + ((size_t)ny * WW + xw * 32) * TT + ln;
    unsigned w = 0u;
#pragma unroll
    for (int x = 0; x < 32; x++) {
        const float v = src[(size_t)x * TT];
        w |= (v != 0.f) ? (1u << x) : 0u;
    }
    bitT[((size_t)ny * XW + xw) * TT + ln] = w;
}

// ---------------- K1: conv1 -> ct1 f32, one wave per 16-px strip -----------
__global__ __launch_bounds__(NT)
void k1_conv1(const unsigned* __restrict__ bitT, const float* __restrict__ w1g,
              float* __restrict__ ct1) {
    __shared__ float lut[5 * 32];
    const int n = blockIdx.z, gy = blockIdx.y * 4 + (threadIdx.x >> 6);
    const int xs = blockIdx.x, ln = threadIdx.x & 63;
    const int tid = threadIdx.x;

    if (tid < 160) {                        // lut[r*32+p] = sum_j w1[r][j]*bit_j(p)
        const int r = tid >> 5, p = tid & 31;
        float s = 0.f;
#pragma unroll
        for (int j = 0; j < 5; j++)
            if ((p >> j) & 1) s += w1g[r * 5 + j];
        lut[tid] = s;
    }

    // Window bits c=0..19 <-> gx = xs*16-2+c, lane = t. Shift s in {30,14}.
    const int x0 = xs * 16;
    const int a = (x0 - 2) >> 5;
    const int s = (x0 - 2) & 31;
    unsigned w20[5];
#pragma unroll
    for (int dy = 0; dy < 5; dy++) {
        const int yy = gy - 2 + dy;
        unsigned wa = 0u, wb = 0u;
        if (yy >= 0 && yy < HH) {
            const unsigned* rp = bitT + ((size_t)(n * HH + yy) * XW) * TT + ln;
            if (a >= 0)     wa = rp[(size_t)a * TT];
            if (a + 1 < XW) wb = rp[(size_t)(a + 1) * TT];
        }
        w20[dy] = (wa >> s) | (wb << (32 - s));
    }
    __syncthreads();

    float* op = ct1 + ((size_t)(n * HH + gy) * SPR + xs) * 16 * TT + ln;
#pragma unroll
    for (int col = 0; col < 16; col++) {
        const float c =
            ((lut[  0 + ((w20[0] >> col) & 31)]
            + lut[ 32 + ((w20[1] >> col) & 31)])
            + (lut[ 64 + ((w20[2] >> col) & 31)]
            +  lut[ 96 + ((w20[3] >> col) & 31)]))
            +  lut[128 + ((w20[4] >> col) & 31)];
        op[(size_t)col * TT] = c;           // 256B coalesced store
    }
}

// ---------------- K2: scan1 (lane = px) -> s1h halfwords -------------------
__global__ __launch_bounds__(NT, 1)
void k2_scan1(const float* __restrict__ ct1, unsigned short* __restrict__ s1h) {
    __shared__ uint2 tb[NT];
    const int n = blockIdx.z, by = blockIdx.y, bx = blockIdx.x;
    const int tid = threadIdx.x;
    const int y = by * 16 + (tid >> 4);

    // per-lane 256B contiguous: 16 x dwordx4 loads into c[64]
    const float4* p = reinterpret_cast<const float4*>(
        ct1 + (((size_t)(n * HH + y) * SPR + bx) * 16 + (tid & 15)) * TT);
    float c[TT];
#pragma unroll
    for (int j = 0; j < 16; j++) {
        const float4 v = p[j];
        c[4 * j + 0] = v.x; c[4 * j + 1] = v.y;
        c[4 * j + 2] = v.z; c[4 * j + 3] = v.w;
    }

    float u1 = 0.f, v1 = 0.f, ur = 0.f, vr = 0.f;
    unsigned slo = 0u, shi = 0u;
#pragma unroll
    for (int tc = 0; tc < TT; tc += 8) {
#pragma unroll
        for (int j = 0; j < 8; j++) {
            v1 = D1 * (v1 + u1);
            const float pp = CP1 * v1;
            u1 = D1 * u1 + c[tc + j];
            vr = DR1 * (vr + ur);
            const float m = pp + CR1 * vr;
            const bool sp = (m >= TH1);
            ur = DR1 * ur + (sp ? 1.f : 0.f);
            const unsigned bit = sp ? (1u << ((tc + j) & 31)) : 0u;
            if (tc < 32) slo |= bit;
            else         shi |= bit;
        }
    }
    tb[tid] = make_uint2(slo, shi);
    __syncthreads();

    // transpose to halfwords, lanes = t (round-5 Phase T)
    const int wv = tid >> 6, ln = tid & 63;
#pragma unroll
    for (int rp = 0; rp < 4; rp++) {
        const int yl = wv * 4 + rp;
        unsigned h = 0u;
#pragma unroll
        for (int x = 0; x < 16; x++) {
            const uint2 b = tb[yl * 16 + x];
            const unsigned w = (ln < 32) ? b.x : b.y;
            h |= ((w >> (ln & 31)) & 1u) << x;
        }
        s1h[((size_t)(n * HH + by * 16 + yl) * XH + bx) * TT + ln] =
            (unsigned short)h;
    }
}

// ---------------- K3: conv2 patterns (9-bit) -> ct2p ushort ----------------
__global__ __launch_bounds__(NT)
void k3_conv2(const unsigned short* __restrict__ s1h,
              unsigned short* __restrict__ ct2p) {
    const int n = blockIdx.z, gy = blockIdx.y * 4 + (threadIdx.x >> 6);
    const int tx = blockIdx.x, ln = threadIdx.x & 63;

    unsigned w18[3];
#pragma unroll
    for (int dy = 0; dy < 3; dy++) {
        const int yy = gy - 1 + dy;
        unsigned hm = 0u, h0 = 0u, hp = 0u;
        if (yy >= 0 && yy < HH) {
            const unsigned short* rp =
                s1h + ((size_t)(n * HH + yy) * XH) * TT + ln;
            if (tx > 0)      hm = rp[(size_t)(tx - 1) * TT];
            h0 = rp[(size_t)tx * TT];
            if (tx + 1 < XH) hp = rp[(size_t)(tx + 1) * TT];
        }
        w18[dy] = (hm >> 15) | (h0 << 1) | ((hp & 1u) << 17);
    }

    unsigned short* op =
        ct2p + ((size_t)(n * HH + gy) * SPR + tx) * 16 * TT + ln;
#pragma unroll
    for (int col = 0; col < 16; col++) {
        const unsigned pat = ((w18[0] >> col) & 7)
                           | (((w18[1] >> col) & 7) << 3)
                           | (((w18[2] >> col) & 7) << 6);
        op[(size_t)col * TT] = (unsigned short)pat;   // 128B coalesced store
    }
}

// ---------------- K4: lut3 gather + scan2 -> coalesced float out -----------
__global__ __launch_bounds__(NT, 1)
void k4_scan2(const unsigned short* __restrict__ ct2p,
              const float* __restrict__ w2g, float* __restrict__ out) {
    __shared__ float lut3[512];
    __shared__ uint2 tb[NT];
    const int n = blockIdx.z, by = blockIdx.y, bx = blockIdx.x;
    const int tid = threadIdx.x;

    // lut3[e] = (l0+l1)+l2, each lk built in j-order -> bitwise = rounds 5/6
#pragma unroll
    for (int e = tid; e < 512; e += NT) {
        float l0 = 0.f, l1 = 0.f, l2 = 0.f;
#pragma unroll
        for (int j = 0; j < 3; j++) {
            if ((e >> j) & 1)       l0 += w2g[j];
            if ((e >> (3 + j)) & 1) l1 += w2g[3 + j];
            if ((e >> (6 + j)) & 1) l2 += w2g[6 + j];
        }
        lut3[e] = (l0 + l1) + l2;
    }
    __syncthreads();

    const int y = by * 16 + (tid >> 4);
    const uint4* pp = reinterpret_cast<const uint4*>(
        ct2p + (((size_t)(n * HH + y) * SPR + bx) * 16 + (tid & 15)) * TT);
    uint4 pr[8];
#pragma unroll
    for (int j = 0; j < 8; j++) pr[j] = pp[j];      // 128B/lane, pipelined

    float l[TT];
#pragma unroll
    for (int j = 0; j < 8; j++) {
        const unsigned q[4] = {pr[j].x, pr[j].y, pr[j].z, pr[j].w};
#pragma unroll
        for (int h = 0; h < 4; h++) {
            l[j * 8 + 2 * h + 0] = lut3[q[h] & 0x1ffu];
            l[j * 8 + 2 * h + 1] = lut3[(q[h] >> 16) & 0x1ffu];
        }
    }

    float u2 = 0.f, v2 = 0.f, ur2 = 0.f, vr2 = 0.f;
    unsigned olo = 0u, ohi = 0u;
#pragma unroll
    for (int tc = 0; tc < TT; tc += 8) {
#pragma unroll
        for (int j = 0; j < 8; j++) {
            v2 = D2 * (v2 + u2);
            const float p = CP2 * v2;
            u2 = D2 * u2 + l[tc + j];
            vr2 = DR2 * (vr2 + ur2);
            const float m = p + CR2 * vr2;
            const bool sp = (m >= TH2);
            ur2 = DR2 * ur2 + (sp ? 1.f : 0.f);
            const unsigned bit = sp ? (1u << ((tc + j) & 31)) : 0u;
            if (tc < 32) olo |= bit;
            else         ohi |= bit;
        }
    }
    tb[tid] = make_uint2(olo, ohi);
    __syncthreads();

    // Epilogue: lanes = t, 256B contiguous stores per wave-instr (round-5 KC).
    const int wv = tid >> 6, ln = tid & 63;
    const int sh = ln & 31;
#pragma unroll
    for (int k = 0; k < 64; k++) {
        const int p = wv * 64 + k;
        const uint2 b = tb[p];                       // LDS broadcast
        const unsigned w = (ln < 32) ? b.x : b.y;
        out[((size_t)(n * HH + by * 16 + (p >> 4)) * WW + bx * 16 + (p & 15)) * TT
            + ln] = (float)((w >> sh) & 1u);
    }
}

extern "C" void kernel_launch(void* const* d_in, const int* in_sizes, int n_in,
                              void* d_out, int out_size, void* d_ws, size_t ws_size,
                              hipStream_t stream) {
    const float* in = (const float*)d_in[0];   // (4,1,192,192,64) f32 spikes
    const float* w1 = (const float*)d_in[1];   // (1,1,5,5)
    const float* w2 = (const float*)d_in[2];   // (1,1,3,3)
    float* out = (float*)d_out;                // (4,1,192,192,64) f32 spikes

    char* ws = (char*)d_ws;
    unsigned*       bitT = (unsigned*)ws;                        // 1.18 MB
    unsigned short* s1h  = (unsigned short*)(ws + (2ull << 20)); // 1.18 MB
    float*          ct1  = (float*)(ws + (4ull << 20));          // 37.7 MB
    unsigned short* ct2p = (unsigned short*)(ws + (44ull << 20));// 18.9 MB

    const int ka_blocks = (NIMG * HH * XW) / (NT / 64);          // 1152
    dim3 cgrid(SPR, HH / 4, NIMG);                               // 12 x 48 x 4
    dim3 sgrid(SPR, HH / 16, NIMG);                              // 12 x 12 x 4
    ka_pack <<<ka_blocks, NT, 0, stream>>>(in, bitT);
    k1_conv1<<<cgrid, NT, 0, stream>>>(bitT, w1, ct1);
    k2_scan1<<<sgrid, NT, 0, stream>>>(ct1, s1h);
    k3_conv2<<<cgrid, NT, 0, stream>>>(s1h, ct2p);
    k4_scan2<<<sgrid, NT, 0, stream>>>(ct2p, w2, out);
}

// Round 8
// 123.726 us; speedup vs baseline: 1.1078x; 1.0183x over previous
//
#include <hip/hip_runtime.h>

// SLAYER 2-layer SNN, MI355X. Round-8: back to 3 fused kernels (round-5
// structure, 2.4 MB intermediates) + cheaper conv phases (round-6/7 tricks).
// psp (temporal LTI, pointwise in space) commutes with conv2d (spatial,
// pointwise in time) -> both convs see BINARY spike trains.
//   KA: floats -> bitT[y][xw][t] (uint32, bit = x%32)           [1152 blocks]
//   KB: conv1 via 2-row LUTs (lutA/lutB 1024 + lutC 32, 3 gathers/px.t)
//       -> ct LDS -> scan1 (lanes=px) -> transpose -> s1h        [576 blocks]
//   KC: conv2 9-bit patterns in regs -> ushort LDS tile -> scan2 with single
//       lut3[512] gather/px.t -> transpose -> coalesced float out [576 blocks]
// All sums keep the association ((l0+l1)+(l2+l3))+l4 and (l0+l1)+l2 of
// rounds 0-7 (absmax == 0 every round).

#define HH   192
#define WW   192
#define NIMG 4
#define TT   64
#define NT   256
#define XW   6     // uint32 x-words per image row
#define XH   12    // 16-bit x-halfwords per image row

#define E_D 2.718281828459045
static constexpr float D1  = (float)0.36787944117144233;   // exp(-1/1)
static constexpr float CP1 = (float)(E_D);
static constexpr float DR1 = (float)0.36787944117144233;
static constexpr float CR1 = (float)(-30.0 * E_D);
static constexpr float D2  = (float)0.6065306597126334;    // exp(-1/2)
static constexpr float CP2 = (float)(E_D * 0.5);
static constexpr float DR2 = (float)0.6065306597126334;
static constexpr float CR2 = (float)(-50.0 * E_D * 0.5);
static constexpr float TH1 = 30.0f;
static constexpr float TH2 = 50.0f;

// ---------------- KA: float spikes -> x-transposed bit words ---------------
__global__ __launch_bounds__(NT)
void ka_pack(const float* __restrict__ in, unsigned* __restrict__ bitT) {
    const int gw = blockIdx.x * (NT / 64) + (threadIdx.x >> 6);
    const int ln = threadIdx.x & 63;
    const int xw = gw % XW;
    const int ny = gw / XW;                 // n*HH + y
    const float* src = in + ((size_t)ny * WW + xw * 32) * TT + ln;
    unsigned w = 0u;
#pragma unroll
    for (int x = 0; x < 32; x++) {
        const float v = src[(size_t)x * TT];
        w |= (v != 0.f) ? (1u << x) : 0u;
    }
    bitT[((size_t)ny * XW + xw) * TT + ln] = w;
}

// ---------------- KB: conv1 (2-row LUTs) + scan1 -> s1h --------------------
__global__ __launch_bounds__(NT, 1)
void kb_layer1(const unsigned* __restrict__ bitT, const float* __restrict__ w1g,
               unsigned short* __restrict__ s1h) {
    __shared__ float lutA[1024];          // rows 0+1: l0(p&31)+l1(p>>5)
    __shared__ float lutB[1024];          // rows 2+3
    __shared__ float lutC[32];            // row 4
    __shared__ float ct[NT * 65];         // conv out [px][t], stride 65
    __shared__ uint2 tb[NT];

    const int n = blockIdx.z, ty = blockIdx.y, tx = blockIdx.x;
    const int y0 = ty * 16, x0 = tx * 16;
    const int tid = threadIdx.x;
    const int wv = tid >> 6, ln = tid & 63;

    // LUT build: per-accumulator j-ascending order == rounds 0-7.
    for (int e = tid; e < 1024; e += NT) {
        float l0 = 0.f, l1 = 0.f, l2 = 0.f, l3 = 0.f;
#pragma unroll
        for (int j = 0; j < 5; j++) {
            if ((e >> j) & 1)       { l0 += w1g[j];     l2 += w1g[10 + j]; }
            if ((e >> (5 + j)) & 1) { l1 += w1g[5 + j]; l3 += w1g[15 + j]; }
        }
        lutA[e] = l0 + l1;
        lutB[e] = l2 + l3;
    }
    if (tid < 32) {
        float s = 0.f;
#pragma unroll
        for (int j = 0; j < 5; j++)
            if ((tid >> j) & 1) s += w1g[20 + j];
        lutC[tid] = s;
    }

    // Register windows from bitT: w20[rr] bits c=0..19 <-> gx = x0-2+c, lane=t.
    const int a = (x0 - 2) >> 5;
    const int s = (x0 - 2) & 31;          // 14 or 30, never 0
    unsigned w20[8];
#pragma unroll
    for (int rr = 0; rr < 8; rr++) {
        const int gy = y0 - 2 + wv * 4 + rr;
        unsigned wa = 0u, wb = 0u;
        if (gy >= 0 && gy < HH) {
            const unsigned* rp = bitT + ((size_t)(n * HH + gy) * XW) * TT + ln;
            if (a >= 0)     wa = rp[(size_t)a * TT];
            if (a + 1 < XW) wb = rp[(size_t)(a + 1) * TT];
        }
        w20[rr] = (wa >> s) | (wb << (32 - s));
    }
    __syncthreads();

    // Conv phase: lanes = t, 3 LDS gathers per px.t.
#pragma unroll
    for (int rp = 0; rp < 4; rp++) {
        const int row = wv * 4 + rp;
#pragma unroll
        for (int col = 0; col < 16; col++) {
            const unsigned pA = ((w20[rp + 0] >> col) & 31)
                              | (((w20[rp + 1] >> col) & 31) << 5);
            const unsigned pB = ((w20[rp + 2] >> col) & 31)
                              | (((w20[rp + 3] >> col) & 31) << 5);
            const unsigned pC = (w20[rp + 4] >> col) & 31;
            ct[(row * 16 + col) * 65 + ln] = (lutA[pA] + lutB[pB]) + lutC[pC];
        }
    }
    __syncthreads();

    // Scan phase: lane = px. Op-identical to rounds 0-7.
    unsigned slo = 0u, shi = 0u;
    {
        const int px = tid;
        float u1 = 0.f, v1 = 0.f, ur = 0.f, vr = 0.f;
#pragma unroll
        for (int tc = 0; tc < TT; tc += 8) {
            float c8[8];
#pragma unroll
            for (int j = 0; j < 8; j++) c8[j] = ct[px * 65 + tc + j];
#pragma unroll
            for (int j = 0; j < 8; j++) {
                v1 = D1 * (v1 + u1);
                const float p = CP1 * v1;
                u1 = D1 * u1 + c8[j];
                vr = DR1 * (vr + ur);
                const float m = p + CR1 * vr;
                const bool sp = (m >= TH1);
                ur = DR1 * ur + (sp ? 1.f : 0.f);
                const unsigned bit = sp ? (1u << ((tc + j) & 31)) : 0u;
                if (tc < 32) slo |= bit;
                else         shi |= bit;
            }
        }
    }
    tb[tid] = make_uint2(slo, shi);
    __syncthreads();

    // Transpose to halfwords, lanes = t (round-5 Phase T).
#pragma unroll
    for (int rp = 0; rp < 4; rp++) {
        const int yl = wv * 4 + rp;
        unsigned h = 0u;
#pragma unroll
        for (int x = 0; x < 16; x++) {
            const uint2 b = tb[yl * 16 + x];
            const unsigned w = (ln < 32) ? b.x : b.y;
            h |= ((w >> (ln & 31)) & 1u) << x;
        }
        s1h[((size_t)(n * HH + y0 + yl) * XH + tx) * TT + ln] =
            (unsigned short)h;
    }
}

// ---------------- KC: conv2 patterns + lut3 scan2 -> float out -------------
__global__ __launch_bounds__(NT, 1)
void kc_layer2(const unsigned short* __restrict__ s1h, const float* __restrict__ w2g,
               float* __restrict__ out) {
    __shared__ float lut3[512];
    __shared__ unsigned short ptile[NT * 66];   // 9-bit patterns [px][t]
    __shared__ uint2 tb[NT];

    const int n = blockIdx.z, ty = blockIdx.y, tx = blockIdx.x;
    const int y0 = ty * 16;
    const int tid = threadIdx.x;
    const int wv = tid >> 6, ln = tid & 63;

    // lut3[e] = (l0+l1)+l2, each lk in j-order -> bitwise = rounds 5-7.
#pragma unroll
    for (int e = tid; e < 512; e += NT) {
        float l0 = 0.f, l1 = 0.f, l2 = 0.f;
#pragma unroll
        for (int j = 0; j < 3; j++) {
            if ((e >> j) & 1)       l0 += w2g[j];
            if ((e >> (3 + j)) & 1) l1 += w2g[3 + j];
            if ((e >> (6 + j)) & 1) l2 += w2g[6 + j];
        }
        lut3[e] = (l0 + l1) + l2;
    }

    // w18[rr] bits c=0..17 <-> gx = tx*16-1+c, from 3 s1 halfwords, lane=t.
    unsigned w18[6];
#pragma unroll
    for (int rr = 0; rr < 6; rr++) {
        const int gy = y0 - 1 + wv * 4 + rr;
        unsigned hm = 0u, h0 = 0u, hp = 0u;
        if (gy >= 0 && gy < HH) {
            const unsigned short* rp = s1h + ((size_t)(n * HH + gy) * XH) * TT + ln;
            if (tx > 0)      hm = rp[(size_t)(tx - 1) * TT];
            h0 = rp[(size_t)tx * TT];
            if (tx + 1 < XH) hp = rp[(size_t)(tx + 1) * TT];
        }
        w18[rr] = (hm >> 15) | (h0 << 1) | ((hp & 1u) << 17);
    }
    __syncthreads();

    // Conv phase: patterns only (no gathers), lanes = t.
#pragma unroll
    for (int rp = 0; rp < 4; rp++) {
        const int row = wv * 4 + rp;
#pragma unroll
        for (int col = 0; col < 16; col++) {
            const unsigned pat = ((w18[rp + 0] >> col) & 7)
                               | (((w18[rp + 1] >> col) & 7) << 3)
                               | (((w18[rp + 2] >> col) & 7) << 6);
            ptile[(row * 16 + col) * 66 + ln] = (unsigned short)pat;
        }
    }
    __syncthreads();

    // Scan phase: lane = px, one lut3 gather per t.
    unsigned olo = 0u, ohi = 0u;
    {
        const int px = tid;
        const unsigned* pp = (const unsigned*)(ptile + px * 66);  // 2 pats/word
        float u2 = 0.f, v2 = 0.f, ur2 = 0.f, vr2 = 0.f;
#pragma unroll
        for (int tc = 0; tc < TT; tc += 8) {
            unsigned q[4];
#pragma unroll
            for (int k = 0; k < 4; k++) q[k] = pp[tc / 2 + k];
            float l[8];
#pragma unroll
            for (int k = 0; k < 4; k++) {
                l[2 * k + 0] = lut3[q[k] & 0x1ffu];
                l[2 * k + 1] = lut3[(q[k] >> 16) & 0x1ffu];
            }
#pragma unroll
            for (int j = 0; j < 8; j++) {
                v2 = D2 * (v2 + u2);
                const float p = CP2 * v2;
                u2 = D2 * u2 + l[j];
                vr2 = DR2 * (vr2 + ur2);
                const float m = p + CR2 * vr2;
                const bool sp = (m >= TH2);
                ur2 = DR2 * ur2 + (sp ? 1.f : 0.f);
                const unsigned bit = sp ? (1u << ((tc + j) & 31)) : 0u;
                if (tc < 32) olo |= bit;
                else         ohi |= bit;
            }
        }
    }
    tb[tid] = make_uint2(olo, ohi);
    __syncthreads();

    // Epilogue: lanes = t, 256B contiguous stores (round-7 K4, verified).
    const int sh = ln & 31;
#pragma unroll
    for (int k = 0; k < 64; k++) {
        const int p = wv * 64 + k;
        const uint2 b = tb[p];                       // LDS broadcast
        const unsigned w = (ln < 32) ? b.x : b.y;
        out[((size_t)(n * HH + y0 + (p >> 4)) * WW + tx * 16 + (p & 15)) * TT
            + ln] = (float)((w >> sh) & 1u);
    }
}

extern "C" void kernel_launch(void* const* d_in, const int* in_sizes, int n_in,
                              void* d_out, int out_size, void* d_ws, size_t ws_size,
                              hipStream_t stream) {
    const float* in = (const float*)d_in[0];   // (4,1,192,192,64) f32 spikes
    const float* w1 = (const float*)d_in[1];   // (1,1,5,5)
    const float* w2 = (const float*)d_in[2];   // (1,1,3,3)
    float* out = (float*)d_out;                // (4,1,192,192,64) f32 spikes

    char* ws = (char*)d_ws;
    unsigned*       bitT = (unsigned*)ws;                        // 1.18 MB
    unsigned short* s1h  = (unsigned short*)(ws + (2ull << 20)); // 1.18 MB

    const int ka_blocks = (NIMG * HH * XW) / (NT / 64);          // 1152
    dim3 tgrid(WW / 16, HH / 16, NIMG);                          // 12 x 12 x 4
    ka_pack  <<<ka_blocks, NT, 0, stream>>>(in, bitT);
    kb_layer1<<<tgrid, NT, 0, stream>>>(bitT, w1, s1h);
    kc_layer2<<<tgrid, NT, 0, stream>>>(s1h, w2, out);
}